// Round 7
// baseline (186.736 us; speedup 1.0000x reference)
//
#include <hip/hip_runtime.h>
#include <hip/hip_bf16.h>
#include <cstdint>
#include <cstddef>

// Problem constants: B=32, N=768, D=768
#define BN_ROWS 24576
#define DD 768
#define BE (768*768)
#define BM 384
#define BN_T 192
#define BK 32
#define ABUF 24576            // A region bytes per buffer (384 rows x 64B)
#define BUFSZ 36864           // A (24576) + B (12288)

typedef __attribute__((ext_vector_type(8))) short bf16x8;
typedef __attribute__((ext_vector_type(4))) float f32x4;

static __device__ __forceinline__ unsigned short f2bf(float f) {
  unsigned int u = __builtin_bit_cast(unsigned int, f);
  unsigned int lsb = (u >> 16) & 1u;
  u += 0x7fffu + lsb;
  return (unsigned short)(u >> 16);
}

// ---------------- conversion kernels ----------------

__global__ __launch_bounds__(256) void convertX(const float* __restrict__ x,
                                                unsigned short* __restrict__ xb, int n4) {
  int idx = blockIdx.x * blockDim.x + threadIdx.x;
  int stride = gridDim.x * blockDim.x;
  for (int i = idx; i < n4; i += stride) {
    float4 v = reinterpret_cast<const float4*>(x)[i];
    ushort4 o;
    o.x = f2bf(v.x); o.y = f2bf(v.y); o.z = f2bf(v.z); o.w = f2bf(v.w);
    reinterpret_cast<ushort4*>(xb)[i] = o;
  }
}

// Transpose+convert via LDS tile (coalesced loads AND stores).
__global__ __launch_bounds__(256) void convertWT(const float* __restrict__ Wl,
                                                 const float* __restrict__ Wl1,
                                                 unsigned short* __restrict__ WlT,
                                                 unsigned short* __restrict__ Wl1T) {
  __shared__ float tile[64][65];
  int tr = blockIdx.x / 12, tc = blockIdx.x % 12;
  int c = threadIdx.x & 63, r0 = threadIdx.x >> 6;
  const float* srcs[2] = {Wl, Wl1};
  unsigned short* dsts[2] = {WlT, Wl1T};
  #pragma unroll
  for (int m = 0; m < 2; ++m) {
    const float* src = srcs[m];
    #pragma unroll
    for (int i = 0; i < 16; ++i) {
      int r = r0 + i * 4;
      tile[r][c] = src[(size_t)(tr * 64 + r) * DD + tc * 64 + c];
    }
    __syncthreads();
    unsigned short* dst = dsts[m];
    #pragma unroll
    for (int i = 0; i < 16; ++i) {
      int r2 = r0 + i * 4;
      dst[(size_t)(tc * 64 + r2) * DD + tr * 64 + c] = f2bf(tile[c][r2]);
    }
    __syncthreads();
  }
}

__global__ __launch_bounds__(256) void adjNorm(const float* __restrict__ adj,
                                               unsigned short* __restrict__ adjnb) {
  int wid = threadIdx.x >> 6, lane = threadIdx.x & 63;
  int row = blockIdx.x * 4 + wid;
  const float4* a = reinterpret_cast<const float4*>(adj + (size_t)row * DD);
  float4 v[3];
  float s = 0.f;
  #pragma unroll
  for (int i = 0; i < 3; ++i) {
    v[i] = a[i * 64 + lane];
    s += (v[i].x + v[i].y) + (v[i].z + v[i].w);
  }
  #pragma unroll
  for (int off = 32; off; off >>= 1) s += __shfl_down(s, off);
  s = __shfl(s, 0);
  float rinv = (s == 0.f) ? 0.f : 1.f / s;
  ushort4* o = reinterpret_cast<ushort4*>(adjnb + (size_t)row * DD);
  #pragma unroll
  for (int i = 0; i < 3; ++i) {
    ushort4 u;
    u.x = f2bf(v[i].x * rinv); u.y = f2bf(v[i].y * rinv);
    u.z = f2bf(v[i].z * rinv); u.w = f2bf(v[i].w * rinv);
    o[i * 64 + lane] = u;
  }
}

// -------- 12-wave 384x192 BK=32 triple-buffered GEMM, 3 waves/SIMD --------
// Wave tile 96x64 (wr=wid&3 rows, wc=wid>>2 cols). acc 96 + frags ~40 regs
// -> <=170 regs -> 3 waves/SIMD: TLP hides LDS read + staging latency.
// Region per K-tile t (ONE barrier): {barrier; 10 ds_read (a*6,b*4);
// stage(t+2) 3 gload_lds; 2x12 MFMA (setprio, counted lgkm); vmcnt(3)}.
// Safety: collective barrier keeps all waves in the same region, so
// stage(t+2)'s writes to buf (t+2)%3 follow all waves' lgkm-drained reads
// of that buf (made in region t-1). vmcnt(3) = counted (stage(t+1) stays
// in flight). Tail stages clamp source to tile 0 to keep counts uniform.
// Swizzle: 16B-slot XOR (row>>1)&3 pre-applied on global source.
// MODE 0: e1 = Xb @ W1T, transposed bf16 store (NT=24)
// MODE 1: out = leaky( adjnb@e1 + Xb@Wl ), fused 48-tile K-loop, fp32 store

template<int MODE>
__global__ __launch_bounds__(768) void gemm12(
    const unsigned short* __restrict__ P0,  // MODE0: Xb     MODE1: adjnb
    const unsigned short* __restrict__ P1,  // MODE0: W1T    MODE1: e1T
    const unsigned short* __restrict__ P2,  // MODE1: Xb
    const unsigned short* __restrict__ P3,  // MODE1: WlT
    void* __restrict__ outp)
{
  __shared__ char smem[3 * BUFSZ];
  constexpr int NT = MODE ? 48 : 24;
  const int tid = threadIdx.x, lane = tid & 63;
  const int wid = tid >> 6;
  const int wr = wid & 3;                   // 0..3 -> 96-row stripe
  const int wc = wid >> 2;                  // 0..2 -> 64-col stripe

  // XCD-chunked logical block id (grid 256 = 8 XCD x 32)
  const int logical = (blockIdx.x & 7) * 32 + (blockIdx.x >> 3);

  const unsigned short *Ab0, *Bb0, *Ab1 = nullptr, *Bb1 = nullptr;
  int mt, nt, b;
  if (MODE == 0) {
    mt = logical >> 2; nt = logical & 3;          // mt 0..63, nt 0..3
    b = mt >> 1;
    Ab0 = P0 + (size_t)mt * BM * DD;
    Bb0 = P1 + (size_t)nt * BN_T * DD;
  } else {
    b = logical >> 3; int r = logical & 7; mt = r >> 2; nt = r & 3;
    size_t bo = (size_t)b * BE;
    Ab0 = P0 + bo + (size_t)mt * BM * DD;   // adjnb
    Bb0 = P1 + bo + (size_t)nt * BN_T * DD; // e1T
    Ab1 = P2 + bo + (size_t)mt * BM * DD;   // Xb
    Bb1 = P3 + (size_t)nt * BN_T * DD;      // WlT
  }

  // staging geometry: 36 chunks of 1KB (16 rows x 64B). Waves 0-7 stage A
  // (chunks 0-23), waves 8-11 stage B (chunks 0-11). 3 chunks per wave.
  const bool isA = wid < 8;
  const int chunk0 = isA ? wid * 3 : (wid - 8) * 3;
  const int ldsbase0 = (isA ? 0 : ABUF) + chunk0 * 1024;
  const int r_in = lane >> 2;                 // row within 16-row chunk
  const int s_in = lane & 3;                  // 16B slot

  auto stage = [&](int s) {
    int sc = s < NT ? s : 0;                  // clamp keeps vmcnt uniform
    const int buf = (s % 3) * BUFSZ;
    const unsigned short* base;
    int kk;
    if (MODE == 1 && sc >= 24) { kk = sc - 24; base = isA ? Ab1 : Bb1; }
    else                       { kk = sc;      base = isA ? Ab0 : Bb0; }
    #pragma unroll
    for (int i = 0; i < 3; ++i) {
      int row = (chunk0 + i) * 16 + r_in;
      int slot = s_in ^ ((row >> 1) & 3);
      const unsigned short* src = base + (size_t)row * DD + kk * BK + slot * 8;
      __builtin_amdgcn_global_load_lds(
          (const __attribute__((address_space(1))) void*)src,
          (__attribute__((address_space(3))) void*)(smem + buf + ldsbase0 + i * 1024),
          16, 0, 0);
    }
  };

  const int ks = lane >> 4;                   // k-slot 0..3 (8 elems each)
  auto frag = [&](int off, int row) -> bf16x8 {
    int slot = ks ^ ((row >> 1) & 3);
    return *reinterpret_cast<const bf16x8*>(smem + off + row * 64 + slot * 16);
  };

  f32x4 acc[6][4] = {};

  // prologue: 2 tiles in flight; wait for tile 0 (3 newest stay outstanding)
  stage(0); stage(1);
  asm volatile("s_waitcnt vmcnt(3)" ::: "memory");

  const int arow = wr * 96 + (lane & 15);
  const int brow = wc * 64 + (lane & 15);

  for (int t = 0; t < NT; ++t) {
    __builtin_amdgcn_s_barrier();
    const int bufA = (t % 3) * BUFSZ;
    const int bufB = bufA + ABUF;

    bf16x8 a[6], bg[4];
    #pragma unroll
    for (int i = 0; i < 6; ++i) a[i] = frag(bufA, arow + i * 16);
    #pragma unroll
    for (int i = 0; i < 4; ++i) bg[i] = frag(bufB, brow + i * 16);

    stage(t + 2);

    __builtin_amdgcn_s_setprio(1);
    #pragma unroll
    for (int ni = 0; ni < 2; ++ni)
      #pragma unroll
      for (int mi = 0; mi < 6; ++mi)
        acc[mi][ni] = __builtin_amdgcn_mfma_f32_16x16x32_bf16(a[mi], bg[ni], acc[mi][ni], 0, 0, 0);
    #pragma unroll
    for (int ni = 2; ni < 4; ++ni)
      #pragma unroll
      for (int mi = 0; mi < 6; ++mi)
        acc[mi][ni] = __builtin_amdgcn_mfma_f32_16x16x32_bf16(a[mi], bg[ni], acc[mi][ni], 0, 0, 0);
    __builtin_amdgcn_s_setprio(0);

    asm volatile("s_waitcnt vmcnt(3)" ::: "memory");   // tile t+1 fully landed
  }

  // ---------------- epilogue ----------------
  if (MODE == 0) {
    unsigned short* ob = (unsigned short*)outp + (size_t)b * BE;
    const int mloc = (mt & 1) * BM + wr * 96 + (lane >> 4) * 4;
    #pragma unroll
    for (int mi = 0; mi < 6; ++mi)
      #pragma unroll
      for (int ni = 0; ni < 4; ++ni) {
        int m = mloc + mi * 16;
        int d = nt * BN_T + wc * 64 + ni * 16 + (lane & 15);
        f32x4 v = acc[mi][ni];
        ushort4 o;
        o.x = f2bf(v[0]); o.y = f2bf(v[1]); o.z = f2bf(v[2]); o.w = f2bf(v[3]);
        *reinterpret_cast<ushort4*>(ob + (size_t)d * DD + m) = o;  // e1T[d][m..m+3]
      }
  } else {
    float* ob = (float*)outp + (size_t)b * BE;
    const int mloc = mt * BM + wr * 96 + (lane >> 4) * 4;
    #pragma unroll
    for (int mi = 0; mi < 6; ++mi)
      #pragma unroll
      for (int ni = 0; ni < 4; ++ni) {
        int m = mloc + mi * 16;
        int n = nt * BN_T + wc * 64 + ni * 16 + (lane & 15);
        f32x4 v = acc[mi][ni];
        #pragma unroll
        for (int j = 0; j < 4; ++j) {
          float x = v[j];
          ob[(size_t)(m + j) * DD + n] = x > 0.f ? x : 0.01f * x;
        }
      }
  }
}

// ---------------- launch ----------------

extern "C" void kernel_launch(void* const* d_in, const int* in_sizes, int n_in,
                              void* d_out, int out_size, void* d_ws, size_t ws_size,
                              hipStream_t stream) {
  const float* X   = (const float*)d_in[0];
  const float* adj = (const float*)d_in[1];
  const float* Wl  = (const float*)d_in[2];
  const float* Wl1 = (const float*)d_in[3];
  float* out = (float*)d_out;

  char* ws = (char*)d_ws;
  const size_t SZ = (size_t)BN_ROWS * DD * 2;   // 37,748,736 bytes
  unsigned short* Xb    = (unsigned short*)(ws);
  unsigned short* adjnb = (unsigned short*)(ws + SZ);
  unsigned short* e1T   = (unsigned short*)(ws + 2 * SZ);
  unsigned short* WlT   = (unsigned short*)(ws + 3 * SZ);
  unsigned short* Wl1T  = (unsigned short*)(ws + 3 * SZ + (size_t)BE * 2);

  convertX<<<4096, 256, 0, stream>>>(X, Xb, (BN_ROWS * DD) / 4);
  convertWT<<<144, 256, 0, stream>>>(Wl, Wl1, WlT, Wl1T);
  adjNorm<<<BN_ROWS / 4, 256, 0, stream>>>(adj, adjnb);
  gemm12<0><<<256, 768, 0, stream>>>(Xb, Wl1T, nullptr, nullptr, e1T);
  gemm12<1><<<256, 768, 0, stream>>>(adjnb, e1T, Xb, WlT, out);
}

// Round 8
// 151.958 us; speedup vs baseline: 1.2289x; 1.2289x over previous
//
#include <hip/hip_runtime.h>
#include <hip/hip_bf16.h>
#include <cstdint>
#include <cstddef>

// Problem constants: B=32, N=768, D=768
#define BN_ROWS 24576
#define DD 768
#define BE (768*768)
#define BM 192
#define BN_T 192
#define BK 32
#define ABUF 12288            // A region bytes per buffer (192 rows x 64B)
#define BUFSZ 24576           // A (12288) + B (12288)

typedef __attribute__((ext_vector_type(8))) short bf16x8;
typedef __attribute__((ext_vector_type(4))) float f32x4;

static __device__ __forceinline__ unsigned short f2bf(float f) {
  unsigned int u = __builtin_bit_cast(unsigned int, f);
  unsigned int lsb = (u >> 16) & 1u;
  u += 0x7fffu + lsb;
  return (unsigned short)(u >> 16);
}

// ---------------- conversion kernels ----------------

__global__ __launch_bounds__(256) void convertX(const float* __restrict__ x,
                                                unsigned short* __restrict__ xb, int n4) {
  int idx = blockIdx.x * blockDim.x + threadIdx.x;
  int stride = gridDim.x * blockDim.x;
  for (int i = idx; i < n4; i += stride) {
    float4 v = reinterpret_cast<const float4*>(x)[i];
    ushort4 o;
    o.x = f2bf(v.x); o.y = f2bf(v.y); o.z = f2bf(v.z); o.w = f2bf(v.w);
    reinterpret_cast<ushort4*>(xb)[i] = o;
  }
}

// Transpose+convert via LDS tile (coalesced loads AND stores).
__global__ __launch_bounds__(256) void convertWT(const float* __restrict__ Wl,
                                                 const float* __restrict__ Wl1,
                                                 unsigned short* __restrict__ WlT,
                                                 unsigned short* __restrict__ Wl1T) {
  __shared__ float tile[64][65];
  int tr = blockIdx.x / 12, tc = blockIdx.x % 12;
  int c = threadIdx.x & 63, r0 = threadIdx.x >> 6;
  const float* srcs[2] = {Wl, Wl1};
  unsigned short* dsts[2] = {WlT, Wl1T};
  #pragma unroll
  for (int m = 0; m < 2; ++m) {
    const float* src = srcs[m];
    #pragma unroll
    for (int i = 0; i < 16; ++i) {
      int r = r0 + i * 4;
      tile[r][c] = src[(size_t)(tr * 64 + r) * DD + tc * 64 + c];
    }
    __syncthreads();
    unsigned short* dst = dsts[m];
    #pragma unroll
    for (int i = 0; i < 16; ++i) {
      int r2 = r0 + i * 4;
      dst[(size_t)(tc * 64 + r2) * DD + tr * 64 + c] = f2bf(tile[c][r2]);
    }
    __syncthreads();
  }
}

__global__ __launch_bounds__(256) void adjNorm(const float* __restrict__ adj,
                                               unsigned short* __restrict__ adjnb) {
  int wid = threadIdx.x >> 6, lane = threadIdx.x & 63;
  int row = blockIdx.x * 4 + wid;
  const float4* a = reinterpret_cast<const float4*>(adj + (size_t)row * DD);
  float4 v[3];
  float s = 0.f;
  #pragma unroll
  for (int i = 0; i < 3; ++i) {
    v[i] = a[i * 64 + lane];
    s += (v[i].x + v[i].y) + (v[i].z + v[i].w);
  }
  #pragma unroll
  for (int off = 32; off; off >>= 1) s += __shfl_down(s, off);
  s = __shfl(s, 0);
  float rinv = (s == 0.f) ? 0.f : 1.f / s;
  ushort4* o = reinterpret_cast<ushort4*>(adjnb + (size_t)row * DD);
  #pragma unroll
  for (int i = 0; i < 3; ++i) {
    ushort4 u;
    u.x = f2bf(v[i].x * rinv); u.y = f2bf(v[i].y * rinv);
    u.z = f2bf(v[i].z * rinv); u.w = f2bf(v[i].w * rinv);
    o[i * 64 + lane] = u;
  }
}

// ----- 4-wave 192x192 BK=32 dbuf GEMM, 2 independent blocks per CU -----
// The fix for R3-R7's 33% plateau: inter-block TLP. 512 blocks = 2/CU;
// when one block drains its vmcnt/barrier, the other block's waves feed
// the MFMA pipe (m114 mechanism, m97's 3-block/CU pattern).
// Per K-tile t: { vmcnt(0) [stage(t) issued a full tile ago -> cheap];
//   s_barrier; 12 ds_read_b128; stage(t+1) 6 gload_lds; 36 MFMA (setprio) }.
// ONE barrier/tile: stage(t+1) writes buf[(t+1)&1], whose readers (tile t-1)
// completed their lgkm-drained reads before the barrier at top of tile t.
// Swizzle: 16B-slot XOR (row>>1)&3 pre-applied on global source (2 lanes/bank
// on frag reads = free per m136); gload_lds dest linear (base+lane*16).
// MODE 0: e1 = Xb @ W1T, transposed bf16 store (NT=24)
// MODE 1: out = leaky( adjnb@e1 + Xb@Wl ), fused 48-tile K-loop, fp32 store

template<int MODE>
__global__ __launch_bounds__(256, 2) void gemm4(
    const unsigned short* __restrict__ P0,  // MODE0: Xb     MODE1: adjnb
    const unsigned short* __restrict__ P1,  // MODE0: W1T    MODE1: e1T
    const unsigned short* __restrict__ P2,  // MODE1: Xb
    const unsigned short* __restrict__ P3,  // MODE1: WlT
    void* __restrict__ outp)
{
  __shared__ char smem[2 * BUFSZ];
  constexpr int NT = MODE ? 48 : 24;
  const int tid = threadIdx.x, lane = tid & 63;
  const int wid = tid >> 6;
  const int wr = wid >> 1, wc = wid & 1;      // wave tile 96x96

  // XCD-chunked bijective logical id (grid 512 = 8 XCD x 64)
  const int logical = (blockIdx.x & 7) * 64 + (blockIdx.x >> 3);

  const unsigned short *Ab0, *Bb0, *Ab1 = nullptr, *Bb1 = nullptr;
  int mt, nt, b;
  if (MODE == 0) {
    mt = logical >> 2; nt = logical & 3;      // mt 0..127, nt 0..3 (nt inner: A-panel shared)
    b = mt >> 2;
    Ab0 = P0 + (size_t)mt * BM * DD;
    Bb0 = P1 + (size_t)nt * BN_T * DD;
  } else {
    b = logical >> 4; int r = logical & 15; mt = r >> 2; nt = r & 3;
    size_t bo = (size_t)b * BE;
    Ab0 = P0 + bo + (size_t)mt * BM * DD;     // adjnb
    Bb0 = P1 + bo + (size_t)nt * BN_T * DD;   // e1T
    Ab1 = P2 + bo + (size_t)mt * BM * DD;     // Xb
    Bb1 = P3 + (size_t)nt * BN_T * DD;        // WlT
  }

  // staging: 24 chunks of 1KB (16 rows x 64B). chunks 0-11 = A, 12-23 = B.
  // wave w stages chunks 6w..6w+5 (wave-uniform A/B split). 6 loads/thread.
  const int r_in = lane >> 2;                 // row within 16-row chunk
  const int s_in = lane & 3;                  // 16B slot

  auto stage = [&](int s) {
    const int buf = (s & 1) * BUFSZ;
    const unsigned short *Ab, *Bb;
    int kk;
    if (MODE == 1 && s >= 24) { kk = s - 24; Ab = Ab1; Bb = Bb1; }
    else                      { kk = s;      Ab = Ab0; Bb = Bb0; }
    #pragma unroll
    for (int i = 0; i < 6; ++i) {
      int chunk = wid * 6 + i;
      bool isA = chunk < 12;                  // wave-uniform
      int c = isA ? chunk : chunk - 12;
      int row = c * 16 + r_in;
      int slot = s_in ^ ((row >> 1) & 3);
      const unsigned short* src = (isA ? Ab : Bb) + (size_t)row * DD + kk * BK + slot * 8;
      __builtin_amdgcn_global_load_lds(
          (const __attribute__((address_space(1))) void*)src,
          (__attribute__((address_space(3))) void*)(smem + buf + (isA ? 0 : ABUF) + c * 1024),
          16, 0, 0);
    }
  };

  const int ks = lane >> 4;                   // k-slot 0..3 (8 elems each)
  auto frag = [&](int off, int row) -> bf16x8 {
    int slot = ks ^ ((row >> 1) & 3);
    return *reinterpret_cast<const bf16x8*>(smem + off + row * 64 + slot * 16);
  };

  f32x4 acc[6][6] = {};
  const int arow = wr * 96 + (lane & 15);
  const int brow = wc * 96 + (lane & 15);

  stage(0);

  for (int t = 0; t < NT; ++t) {
    asm volatile("s_waitcnt vmcnt(0)" ::: "memory");  // tile t landed (issued 1 tile ago)
    __builtin_amdgcn_s_barrier();

    const int bufA = (t & 1) * BUFSZ;
    const int bufB = bufA + ABUF;
    bf16x8 a[6], bg[6];
    #pragma unroll
    for (int i = 0; i < 6; ++i) a[i] = frag(bufA, arow + i * 16);
    #pragma unroll
    for (int i = 0; i < 6; ++i) bg[i] = frag(bufB, brow + i * 16);

    if (t + 1 < NT) stage(t + 1);

    __builtin_amdgcn_s_setprio(1);
    #pragma unroll
    for (int mi = 0; mi < 6; ++mi)
      #pragma unroll
      for (int ni = 0; ni < 6; ++ni)
        acc[mi][ni] = __builtin_amdgcn_mfma_f32_16x16x32_bf16(a[mi], bg[ni], acc[mi][ni], 0, 0, 0);
    __builtin_amdgcn_s_setprio(0);
  }

  // ---------------- epilogue ----------------
  if (MODE == 0) {
    unsigned short* ob = (unsigned short*)outp + (size_t)b * BE;
    const int mloc = (mt & 3) * BM + wr * 96 + (lane >> 4) * 4;
    #pragma unroll
    for (int mi = 0; mi < 6; ++mi)
      #pragma unroll
      for (int ni = 0; ni < 6; ++ni) {
        int m = mloc + mi * 16;
        int d = nt * BN_T + wc * 96 + ni * 16 + (lane & 15);
        f32x4 v = acc[mi][ni];
        ushort4 o;
        o.x = f2bf(v[0]); o.y = f2bf(v[1]); o.z = f2bf(v[2]); o.w = f2bf(v[3]);
        *reinterpret_cast<ushort4*>(ob + (size_t)d * DD + m) = o;  // e1T[d][m..m+3]
      }
  } else {
    float* ob = (float*)outp + (size_t)b * BE;
    const int mloc = mt * BM + wr * 96 + (lane >> 4) * 4;
    #pragma unroll
    for (int mi = 0; mi < 6; ++mi)
      #pragma unroll
      for (int ni = 0; ni < 6; ++ni) {
        int m = mloc + mi * 16;
        int n = nt * BN_T + wc * 96 + ni * 16 + (lane & 15);
        f32x4 v = acc[mi][ni];
        #pragma unroll
        for (int j = 0; j < 4; ++j) {
          float x = v[j];
          ob[(size_t)(m + j) * DD + n] = x > 0.f ? x : 0.01f * x;
        }
      }
  }
}

// ---------------- launch ----------------

extern "C" void kernel_launch(void* const* d_in, const int* in_sizes, int n_in,
                              void* d_out, int out_size, void* d_ws, size_t ws_size,
                              hipStream_t stream) {
  const float* X   = (const float*)d_in[0];
  const float* adj = (const float*)d_in[1];
  const float* Wl  = (const float*)d_in[2];
  const float* Wl1 = (const float*)d_in[3];
  float* out = (float*)d_out;

  char* ws = (char*)d_ws;
  const size_t SZ = (size_t)BN_ROWS * DD * 2;   // 37,748,736 bytes
  unsigned short* Xb    = (unsigned short*)(ws);
  unsigned short* adjnb = (unsigned short*)(ws + SZ);
  unsigned short* e1T   = (unsigned short*)(ws + 2 * SZ);
  unsigned short* WlT   = (unsigned short*)(ws + 3 * SZ);
  unsigned short* Wl1T  = (unsigned short*)(ws + 3 * SZ + (size_t)BE * 2);

  convertX<<<4096, 256, 0, stream>>>(X, Xb, (BN_ROWS * DD) / 4);
  convertWT<<<144, 256, 0, stream>>>(Wl, Wl1, WlT, Wl1T);
  adjNorm<<<BN_ROWS / 4, 256, 0, stream>>>(adj, adjnb);
  gemm4<0><<<512, 256, 0, stream>>>(Xb, Wl1T, nullptr, nullptr, e1T);
  gemm4<1><<<512, 256, 0, stream>>>(adjnb, e1T, Xb, WlT, out);
}

// Round 9
// 146.644 us; speedup vs baseline: 1.2734x; 1.0362x over previous
//
#include <hip/hip_runtime.h>
#include <hip/hip_bf16.h>
#include <cstdint>
#include <cstddef>

// Problem constants: B=32, N=768, D=768
#define BN_ROWS 24576
#define DD 768
#define BE (768*768)
#define BM 192
#define BN_T 192
#define BK 32
#define ABUF 12288            // A region bytes per buffer (192 rows x 64B)
#define BUFSZ 24576           // A (12288) + B (12288)

typedef __attribute__((ext_vector_type(8))) short bf16x8;
typedef __attribute__((ext_vector_type(4))) float f32x4;

static __device__ __forceinline__ unsigned short f2bf(float f) {
  unsigned int u = __builtin_bit_cast(unsigned int, f);
  unsigned int lsb = (u >> 16) & 1u;
  u += 0x7fffu + lsb;
  return (unsigned short)(u >> 16);
}

// ---------------- fused prep kernel ----------------
// Sections by blockIdx: [0,4096) convertX (grid-stride), [4096,4240)
// convertWT (64x64 LDS transpose tiles), [4240,10384) adjNorm (4 rows/block).
// One launch: all three memory-bound streams saturate HBM concurrently.

#define PREP_CX 4096
#define PREP_WT 144
#define PREP_AN 6144

__global__ __launch_bounds__(256) void prep(const float* __restrict__ X,
                                            const float* __restrict__ adj,
                                            const float* __restrict__ Wl,
                                            const float* __restrict__ Wl1,
                                            unsigned short* __restrict__ Xb,
                                            unsigned short* __restrict__ adjnb,
                                            unsigned short* __restrict__ WlT,
                                            unsigned short* __restrict__ Wl1T) {
  __shared__ float tile[64][65];
  const int bid = blockIdx.x;

  if (bid < PREP_CX) {
    const int n4 = (BN_ROWS * DD) / 4;
    for (int i = bid * 256 + threadIdx.x; i < n4; i += PREP_CX * 256) {
      float4 v = reinterpret_cast<const float4*>(X)[i];
      ushort4 o;
      o.x = f2bf(v.x); o.y = f2bf(v.y); o.z = f2bf(v.z); o.w = f2bf(v.w);
      reinterpret_cast<ushort4*>(Xb)[i] = o;
    }
  } else if (bid < PREP_CX + PREP_WT) {
    const int tb = bid - PREP_CX;
    const int tr = tb / 12, tc = tb % 12;
    const int c = threadIdx.x & 63, r0 = threadIdx.x >> 6;
    const float* srcs[2] = {Wl, Wl1};
    unsigned short* dsts[2] = {WlT, Wl1T};
    #pragma unroll
    for (int m = 0; m < 2; ++m) {
      const float* src = srcs[m];
      #pragma unroll
      for (int i = 0; i < 16; ++i) {
        int r = r0 + i * 4;
        tile[r][c] = src[(size_t)(tr * 64 + r) * DD + tc * 64 + c];
      }
      __syncthreads();
      unsigned short* dst = dsts[m];
      #pragma unroll
      for (int i = 0; i < 16; ++i) {
        int r2 = r0 + i * 4;
        dst[(size_t)(tc * 64 + r2) * DD + tr * 64 + c] = f2bf(tile[c][r2]);
      }
      __syncthreads();
    }
  } else {
    const int rb = bid - (PREP_CX + PREP_WT);
    const int wid = threadIdx.x >> 6, lane = threadIdx.x & 63;
    const int row = rb * 4 + wid;
    const float4* a = reinterpret_cast<const float4*>(adj + (size_t)row * DD);
    float4 v[3];
    float s = 0.f;
    #pragma unroll
    for (int i = 0; i < 3; ++i) {
      v[i] = a[i * 64 + lane];
      s += (v[i].x + v[i].y) + (v[i].z + v[i].w);
    }
    #pragma unroll
    for (int off = 32; off; off >>= 1) s += __shfl_down(s, off);
    s = __shfl(s, 0);
    float rinv = (s == 0.f) ? 0.f : 1.f / s;
    ushort4* o = reinterpret_cast<ushort4*>(adjnb + (size_t)row * DD);
    #pragma unroll
    for (int i = 0; i < 3; ++i) {
      ushort4 u;
      u.x = f2bf(v[i].x * rinv); u.y = f2bf(v[i].y * rinv);
      u.z = f2bf(v[i].z * rinv); u.w = f2bf(v[i].w * rinv);
      o[i * 64 + lane] = u;
    }
  }
}

// ----- 4-wave 192x192 BK=32 dbuf GEMM, 2 independent blocks per CU -----
// R8 + two scheduling fixes:
// (a) stage(t+1) issued at tile TOP (max VMEM slack; race-free: all waves'
//     t-1 ds_reads were lgkm-consumed by their MFMAs before the barrier).
// (b) reads ordered a0..a5,b0..b5 with MFMA clusters ni-outer/mi-inner:
//     cluster ni needs reads 1..7+ni -> compiler's counted lgkmcnt drains
//     progressively UNDER earlier clusters' MFMA instead of a full drain.
// MODE 0: e1 = Xb @ W1T, transposed bf16 store (NT=24)
// MODE 1: out = leaky( adjnb@e1 + Xb@Wl ), fused 48-tile K-loop, fp32 store

template<int MODE>
__global__ __launch_bounds__(256, 2) void gemm4(
    const unsigned short* __restrict__ P0,  // MODE0: Xb     MODE1: adjnb
    const unsigned short* __restrict__ P1,  // MODE0: W1T    MODE1: e1T
    const unsigned short* __restrict__ P2,  // MODE1: Xb
    const unsigned short* __restrict__ P3,  // MODE1: WlT
    void* __restrict__ outp)
{
  __shared__ char smem[2 * BUFSZ];
  constexpr int NT = MODE ? 48 : 24;
  const int tid = threadIdx.x, lane = tid & 63;
  const int wid = tid >> 6;
  const int wr = wid >> 1, wc = wid & 1;      // wave tile 96x96

  // XCD-chunked bijective logical id (grid 512 = 8 XCD x 64)
  const int logical = (blockIdx.x & 7) * 64 + (blockIdx.x >> 3);

  const unsigned short *Ab0, *Bb0, *Ab1 = nullptr, *Bb1 = nullptr;
  int mt, nt, b;
  if (MODE == 0) {
    mt = logical >> 2; nt = logical & 3;      // mt 0..127, nt 0..3 (nt inner: A-panel shared)
    b = mt >> 2;
    Ab0 = P0 + (size_t)mt * BM * DD;
    Bb0 = P1 + (size_t)nt * BN_T * DD;
  } else {
    b = logical >> 4; int r = logical & 15; mt = r >> 2; nt = r & 3;
    size_t bo = (size_t)b * BE;
    Ab0 = P0 + bo + (size_t)mt * BM * DD;     // adjnb
    Bb0 = P1 + bo + (size_t)nt * BN_T * DD;   // e1T
    Ab1 = P2 + bo + (size_t)mt * BM * DD;     // Xb
    Bb1 = P3 + (size_t)nt * BN_T * DD;        // WlT
  }

  // staging: 24 chunks of 1KB (16 rows x 64B). chunks 0-11 = A, 12-23 = B.
  // wave w stages chunks 6w..6w+5 (wave-uniform A/B split). 6 loads/thread.
  const int r_in = lane >> 2;                 // row within 16-row chunk
  const int s_in = lane & 3;                  // 16B slot

  auto stage = [&](int s) {
    const int buf = (s & 1) * BUFSZ;
    const unsigned short *Ab, *Bb;
    int kk;
    if (MODE == 1 && s >= 24) { kk = s - 24; Ab = Ab1; Bb = Bb1; }
    else                      { kk = s;      Ab = Ab0; Bb = Bb0; }
    #pragma unroll
    for (int i = 0; i < 6; ++i) {
      int chunk = wid * 6 + i;
      bool isA = chunk < 12;                  // wave-uniform
      int c = isA ? chunk : chunk - 12;
      int row = c * 16 + r_in;
      int slot = s_in ^ ((row >> 1) & 3);
      const unsigned short* src = (isA ? Ab : Bb) + (size_t)row * DD + kk * BK + slot * 8;
      __builtin_amdgcn_global_load_lds(
          (const __attribute__((address_space(1))) void*)src,
          (__attribute__((address_space(3))) void*)(smem + buf + (isA ? 0 : ABUF) + c * 1024),
          16, 0, 0);
    }
  };

  const int ks = lane >> 4;                   // k-slot 0..3 (8 elems each)
  auto frag = [&](int off, int row) -> bf16x8 {
    int slot = ks ^ ((row >> 1) & 3);
    return *reinterpret_cast<const bf16x8*>(smem + off + row * 64 + slot * 16);
  };

  f32x4 acc[6][6] = {};
  const int arow = wr * 96 + (lane & 15);
  const int brow = wc * 96 + (lane & 15);

  stage(0);

  for (int t = 0; t < NT; ++t) {
    asm volatile("s_waitcnt vmcnt(0)" ::: "memory");  // tile t landed (issued 1 tile ago)
    __builtin_amdgcn_s_barrier();

    if (t + 1 < NT) stage(t + 1);            // issue next tile ASAP (max slack)

    const int bufA = (t & 1) * BUFSZ;
    const int bufB = bufA + ABUF;
    bf16x8 a[6], bg[6];
    #pragma unroll
    for (int i = 0; i < 6; ++i) a[i] = frag(bufA, arow + i * 16);
    #pragma unroll
    for (int i = 0; i < 6; ++i) bg[i] = frag(bufB, brow + i * 16);

    __builtin_amdgcn_s_setprio(1);
    #pragma unroll
    for (int ni = 0; ni < 6; ++ni)           // ni outer: cluster ni needs b[ni] only
      #pragma unroll
      for (int mi = 0; mi < 6; ++mi)
        acc[mi][ni] = __builtin_amdgcn_mfma_f32_16x16x32_bf16(a[mi], bg[ni], acc[mi][ni], 0, 0, 0);
    __builtin_amdgcn_s_setprio(0);
  }

  // ---------------- epilogue ----------------
  if (MODE == 0) {
    unsigned short* ob = (unsigned short*)outp + (size_t)b * BE;
    const int mloc = (mt & 3) * BM + wr * 96 + (lane >> 4) * 4;
    #pragma unroll
    for (int mi = 0; mi < 6; ++mi)
      #pragma unroll
      for (int ni = 0; ni < 6; ++ni) {
        int m = mloc + mi * 16;
        int d = nt * BN_T + wc * 96 + ni * 16 + (lane & 15);
        f32x4 v = acc[mi][ni];
        ushort4 o;
        o.x = f2bf(v[0]); o.y = f2bf(v[1]); o.z = f2bf(v[2]); o.w = f2bf(v[3]);
        *reinterpret_cast<ushort4*>(ob + (size_t)d * DD + m) = o;  // e1T[d][m..m+3]
      }
  } else {
    float* ob = (float*)outp + (size_t)b * BE;
    const int mloc = mt * BM + wr * 96 + (lane >> 4) * 4;
    #pragma unroll
    for (int mi = 0; mi < 6; ++mi)
      #pragma unroll
      for (int ni = 0; ni < 6; ++ni) {
        int m = mloc + mi * 16;
        int n = nt * BN_T + wc * 96 + ni * 16 + (lane & 15);
        f32x4 v = acc[mi][ni];
        #pragma unroll
        for (int j = 0; j < 4; ++j) {
          float x = v[j];
          ob[(size_t)(m + j) * DD + n] = x > 0.f ? x : 0.01f * x;
        }
      }
  }
}

// ---------------- launch ----------------

extern "C" void kernel_launch(void* const* d_in, const int* in_sizes, int n_in,
                              void* d_out, int out_size, void* d_ws, size_t ws_size,
                              hipStream_t stream) {
  const float* X   = (const float*)d_in[0];
  const float* adj = (const float*)d_in[1];
  const float* Wl  = (const float*)d_in[2];
  const float* Wl1 = (const float*)d_in[3];
  float* out = (float*)d_out;

  char* ws = (char*)d_ws;
  const size_t SZ = (size_t)BN_ROWS * DD * 2;   // 37,748,736 bytes
  unsigned short* Xb    = (unsigned short*)(ws);
  unsigned short* adjnb = (unsigned short*)(ws + SZ);
  unsigned short* e1T   = (unsigned short*)(ws + 2 * SZ);
  unsigned short* WlT   = (unsigned short*)(ws + 3 * SZ);
  unsigned short* Wl1T  = (unsigned short*)(ws + 3 * SZ + (size_t)BE * 2);

  prep<<<PREP_CX + PREP_WT + PREP_AN, 256, 0, stream>>>(X, adj, Wl, Wl1,
                                                        Xb, adjnb, WlT, Wl1T);
  gemm4<0><<<512, 256, 0, stream>>>(Xb, Wl1T, nullptr, nullptr, e1T);
  gemm4<1><<<512, 256, 0, stream>>>(adjnb, e1T, Xb, WlT, out);
}